// Round 2
// baseline (463.963 us; speedup 1.0000x reference)
//
#include <hip/hip_runtime.h>

// LSTMNet: SEQ=600, B=4096, IN=6, H=30, OUT=61, fp32.
// Layout A2: one wave = one batch element. lane = 32*half + u.
//   half 0, lane u<30: gate rows i (0*30+u) and f (1*30+u)
//   half 1, lane u<30: gate rows g (2*30+u) and o (3*30+u)
// Each lane holds its 2 gate rows packed pairwise over k as float2 -> v_pk_fma_f32.
// h broadcast via 32-float LDS row per element; cross-half exchange via shfl_xor(32).
// No block barriers (waves independent). 4 waves/SIMD occupancy target.

#define SEQ   600
#define BATCH 4096
#define INP   6
#define HID   30
#define NOUT  61
#define EPW   1   // elements per wave
#define WPB   4   // waves per block

typedef float f32x2 __attribute__((ext_vector_type(2)));

__device__ __forceinline__ float rcp_(float x) { return __builtin_amdgcn_rcpf(x); }
__device__ __forceinline__ float exp2_(float x) { return __builtin_amdgcn_exp2f(x); }

extern "C" __global__ void __launch_bounds__(256, 4)
lstm_fused2(const float* __restrict__ X,   const float* __restrict__ Wih,
            const float* __restrict__ Whh, const float* __restrict__ bih,
            const float* __restrict__ bhh, const float* __restrict__ W1,
            const float* __restrict__ b1,  const float* __restrict__ W2,
            const float* __restrict__ b2,  float* __restrict__ out)
{
    __shared__ float h_sh[WPB][32];   // per-element h row (pads [30..31] stay 0)
    __shared__ float o1_sh[WPB][32];  // fc1 activations

    const int tid  = threadIdx.x;
    const int lane = tid & 63;
    const int u    = lane & 31;            // hidden unit (active u < 30)
    const int half = lane >> 5;            // 0: gates (i,f); 1: gates (g,o)
    const int e    = __builtin_amdgcn_readfirstlane(tid >> 6);  // wave slot, uniform
    const int b    = blockIdx.x * WPB + e; // batch element (wave-uniform)
    const bool act = (u < HID);

    if (lane < 32) h_sh[e][lane] = 0.0f;

    // ---- per-lane weights, packed over k pairs ----
    const int rowA = (half * 2 + 0) * HID + u;   // i or g
    const int rowB = (half * 2 + 1) * HID + u;   // f or o

    f32x2 wA[16], wB[16];
    f32x2 xA[3], xB[3];
    float bA = 0.f, bB = 0.f;
    #pragma unroll
    for (int j = 0; j < 16; ++j) { wA[j] = (f32x2)0.f; wB[j] = (f32x2)0.f; }
    #pragma unroll
    for (int j = 0; j < 3; ++j) { xA[j] = (f32x2)0.f; xB[j] = (f32x2)0.f; }

    if (act) {
        const float* ra = Whh + rowA * HID;
        const float* rb = Whh + rowB * HID;
        #pragma unroll
        for (int j = 0; j < 15; ++j) {
            wA[j] = f32x2{ra[2*j], ra[2*j+1]};
            wB[j] = f32x2{rb[2*j], rb[2*j+1]};
        }
        const float* va = Wih + rowA * INP;
        const float* vb = Wih + rowB * INP;
        #pragma unroll
        for (int j = 0; j < 3; ++j) {
            xA[j] = f32x2{va[2*j], va[2*j+1]};
            xB[j] = f32x2{vb[2*j], vb[2*j+1]};
        }
        bA = bih[rowA] + bhh[rowA];
        bB = bih[rowB] + bhh[rowB];
    }

    // per-lane nonlinearity constants (branchless tanh-vs-sigmoid):
    //   half0: nA = sigm(aA)          = 1*rcp(1+exp2(-1.4427*aA)) + 0
    //   half1: nA = tanh(aA)          = 2*rcp(1+exp2(-2.8854*aA)) - 1
    const float mA = half ? -2.8853900818f : -1.4426950409f;
    const float sA = half ? 2.0f : 1.0f;
    const float cA = half ? -1.0f : 0.0f;

    float c = 0.f, h = 0.f;
    f32x2 x2[3], xn2[3];
    {
        const f32x2* p = (const f32x2*)(X + (size_t)b * INP);  // t = 0
        #pragma unroll
        for (int j = 0; j < 3; ++j) x2[j] = p[j];
    }
    asm volatile("s_waitcnt lgkmcnt(0)" ::: "memory");  // h_sh init visible

    const f32x2* h2 = (const f32x2*)(&h_sh[e][0]);

    for (int t = 0; t < SEQ; ++t) {
        if (t + 1 < SEQ) {
            const f32x2* p = (const f32x2*)(X + ((size_t)(t + 1) * BATCH + b) * INP);
            #pragma unroll
            for (int j = 0; j < 3; ++j) xn2[j] = p[j];
        }

        f32x2 accA = f32x2{bA, 0.f};
        f32x2 accB = f32x2{bB, 0.f};
        #pragma unroll
        for (int j = 0; j < 16; ++j) {
            f32x2 hv = h2[j];
            accA = __builtin_elementwise_fma(wA[j], hv, accA);
            accB = __builtin_elementwise_fma(wB[j], hv, accB);
        }
        #pragma unroll
        for (int j = 0; j < 3; ++j) {
            accA = __builtin_elementwise_fma(xA[j], x2[j], accA);
            accB = __builtin_elementwise_fma(xB[j], x2[j], accB);
        }
        const float aA = accA.x + accA.y;
        const float aB = accB.x + accB.y;

        // half0: nA=sigm_i, nB=sigm_f ; half1: nA=tanh_g, nB=sigm_o
        const float nA = fmaf(sA, rcp_(1.0f + exp2_(mA * aA)), cA);
        const float nB = rcp_(1.0f + exp2_(-1.4426950409f * aB));

        const float vA = __shfl_xor(nA, 32);
        const float vB = __shfl_xor(nB, 32);

        // c = F*c + nA*vA   (both halves: nA*vA == sigm_i * tanh_g)
        const float F = half ? vB : nB;   // sigm_f
        const float O = half ? nB : vB;   // sigm_o
        c = fmaf(F, c, nA * vA);
        const float tc = 1.0f - 2.0f * rcp_(exp2_(2.8853900818f * c) + 1.0f);
        h = O * tc;

        if (lane < HID) h_sh[e][lane] = h;   // low half writes
        asm volatile("s_waitcnt lgkmcnt(0)" ::: "memory");

        #pragma unroll
        for (int j = 0; j < 3; ++j) x2[j] = xn2[j];
    }

    // ---- FC1 (lanes 0..29): o1[u] = b1[u] + sum_k W1[u,k] * h[k] ----
    if (lane < HID) {
        float a1 = b1[lane];
        const float* w1r = W1 + lane * HID;
        #pragma unroll
        for (int k = 0; k < HID; ++k) a1 = fmaf(w1r[k], h_sh[e][k], a1);
        o1_sh[e][lane] = a1;
    }
    asm volatile("s_waitcnt lgkmcnt(0)" ::: "memory");

    // ---- FC2 (lanes 0..60): out[o] = b2[o] + sum_j W2[o,j] * o1[j] ----
    if (lane < NOUT) {
        float a2 = b2[lane];
        const float* w2r = W2 + lane * HID;
        #pragma unroll
        for (int k = 0; k < HID; ++k) a2 = fmaf(w2r[k], o1_sh[e][k], a2);
        out[(size_t)b * NOUT + lane] = a2;
    }
}

extern "C" void kernel_launch(void* const* d_in, const int* in_sizes, int n_in,
                              void* d_out, int out_size, void* d_ws, size_t ws_size,
                              hipStream_t stream) {
    const float* X   = (const float*)d_in[0];
    const float* Wih = (const float*)d_in[1];
    const float* Whh = (const float*)d_in[2];
    const float* bih = (const float*)d_in[3];
    const float* bhh = (const float*)d_in[4];
    const float* W1  = (const float*)d_in[5];
    const float* b1  = (const float*)d_in[6];
    const float* W2  = (const float*)d_in[7];
    const float* b2  = (const float*)d_in[8];
    float* out = (float*)d_out;

    dim3 grid(BATCH / WPB);   // 1024 blocks
    dim3 block(64 * WPB);     // 4 waves = 4 elements
    hipLaunchKernelGGL(lstm_fused2, grid, block, 0, stream,
                       X, Wih, Whh, bih, bhh, W1, b1, W2, b2, out);
}

// Round 3
// 450.166 us; speedup vs baseline: 1.0306x; 1.0306x over previous
//
#include <hip/hip_runtime.h>

// LSTMNet: SEQ=600, B=4096, IN=6, H=30, OUT=61, fp32.
// Layout A2 + register pinning. One wave = one batch element; lane = 32*half + u.
//   half 0, u<30: gate rows i,f    half 1, u<30: gate rows g,o
// Each lane holds its 2 gate rows packed pairwise (f32x2 -> v_pk_fma_f32),
// PINNED into VGPRs via opaque asm so the compiler cannot rematerialize the
// loads inside the 600-step loop (round-2 failure mode: VGPR=48, FETCH 2x).
// h broadcast via 32-float LDS row; cross-half exchange via shfl_xor(32).

#define SEQ   600
#define BATCH 4096
#define INP   6
#define HID   30
#define NOUT  61
#define WPB   4   // waves (= batch elements) per block

typedef float f32x2 __attribute__((ext_vector_type(2)));

__device__ __forceinline__ float rcp_(float x) { return __builtin_amdgcn_rcpf(x); }
__device__ __forceinline__ float exp2_(float x) { return __builtin_amdgcn_exp2f(x); }

extern "C" __global__ void __launch_bounds__(256, 2)
lstm_fused3(const float* __restrict__ X,   const float* __restrict__ Wih,
            const float* __restrict__ Whh, const float* __restrict__ bih,
            const float* __restrict__ bhh, const float* __restrict__ W1,
            const float* __restrict__ b1,  const float* __restrict__ W2,
            const float* __restrict__ b2,  float* __restrict__ out)
{
    __shared__ float h_sh[WPB][32];   // per-element h row (pads [30..31] stay 0)
    __shared__ float o1_sh[WPB][32];  // fc1 activations

    const int tid  = threadIdx.x;
    const int lane = tid & 63;
    const int u    = lane & 31;            // hidden unit (active u < 30)
    const int half = lane >> 5;            // 0: gates (i,f); 1: gates (g,o)
    const int e    = __builtin_amdgcn_readfirstlane(tid >> 6);  // wave slot
    const int b    = blockIdx.x * WPB + e; // batch element (wave-uniform)
    const bool act = (u < HID);

    if (lane < 32) h_sh[e][lane] = 0.0f;

    // ---- per-lane weights, packed over k pairs (15 pairs cover k=0..29) ----
    const int rowA = (half * 2 + 0) * HID + u;   // i or g
    const int rowB = (half * 2 + 1) * HID + u;   // f or o

    f32x2 wA[15], wB[15];
    f32x2 xA[3], xB[3];
    float bA = 0.f, bB = 0.f;
    #pragma unroll
    for (int j = 0; j < 15; ++j) { wA[j] = (f32x2)0.f; wB[j] = (f32x2)0.f; }
    #pragma unroll
    for (int j = 0; j < 3; ++j) { xA[j] = (f32x2)0.f; xB[j] = (f32x2)0.f; }

    if (act) {
        const float* ra = Whh + rowA * HID;
        const float* rb = Whh + rowB * HID;
        #pragma unroll
        for (int j = 0; j < 15; ++j) {
            wA[j] = f32x2{ra[2*j], ra[2*j+1]};
            wB[j] = f32x2{rb[2*j], rb[2*j+1]};
        }
        const float* va = Wih + rowA * INP;
        const float* vb = Wih + rowB * INP;
        #pragma unroll
        for (int j = 0; j < 3; ++j) {
            xA[j] = f32x2{va[2*j], va[2*j+1]};
            xB[j] = f32x2{vb[2*j], vb[2*j+1]};
        }
        bA = bih[rowA] + bhh[rowA];
        bB = bih[rowB] + bhh[rowB];
    }

    // ---- PIN: make weight values opaque so they stay VGPR-resident ----
    #pragma unroll
    for (int j = 0; j < 15; ++j) asm volatile("" : "+v"(wA[j]), "+v"(wB[j]));
    #pragma unroll
    for (int j = 0; j < 3; ++j)  asm volatile("" : "+v"(xA[j]), "+v"(xB[j]));
    asm volatile("" : "+v"(bA), "+v"(bB));

    // per-lane nonlinearity constants (branchless tanh-vs-sigmoid):
    //   half0: nA = sigm(aA);  half1: nA = tanh(aA) = 2*sigm(2aA)-1
    const float mA = half ? -2.8853900818f : -1.4426950409f;
    const float sA = half ? 2.0f : 1.0f;
    const float cA = half ? -1.0f : 0.0f;

    float c = 0.f, h = 0.f;

    // x is wave-uniform (same 6 floats for all lanes) -> scalar loads.
    float x0, x1, x2v, x3, x4, x5;
    {
        const float* p = X + (size_t)b * INP;   // t = 0
        x0 = p[0]; x1 = p[1]; x2v = p[2]; x3 = p[3]; x4 = p[4]; x5 = p[5];
    }
    asm volatile("s_waitcnt lgkmcnt(0)" ::: "memory");  // h_sh init visible

    const float4* h4p = (const float4*)(&h_sh[e][0]);
    const f32x2*  h2p = (const f32x2*)(&h_sh[e][0]);

    for (int t = 0; t < SEQ; ++t) {
        // prefetch x for t+1 (branchless clamp; wave-uniform address)
        const int tn = (t + 1 < SEQ) ? (t + 1) : (SEQ - 1);
        const float* p = X + ((size_t)tn * BATCH + b) * INP;
        float y0 = p[0], y1 = p[1], y2 = p[2], y3 = p[3], y4 = p[4], y5 = p[5];

        // h reads: 7x float4 (k0..27) + 1x float2 (k28,29)
        float4 H0 = h4p[0], H1 = h4p[1], H2 = h4p[2], H3 = h4p[3];
        float4 H4 = h4p[4], H5 = h4p[5], H6 = h4p[6];
        f32x2  Ht = h2p[14];

        f32x2 accA = f32x2{bA, 0.f};
        f32x2 accB = f32x2{bB, 0.f};
        #define PKFMA(J, HX, HY) do {                                   \
            f32x2 hv = f32x2{HX, HY};                                   \
            accA = __builtin_elementwise_fma(wA[J], hv, accA);          \
            accB = __builtin_elementwise_fma(wB[J], hv, accB);          \
        } while (0)
        PKFMA(0,  H0.x, H0.y); PKFMA(1,  H0.z, H0.w);
        PKFMA(2,  H1.x, H1.y); PKFMA(3,  H1.z, H1.w);
        PKFMA(4,  H2.x, H2.y); PKFMA(5,  H2.z, H2.w);
        PKFMA(6,  H3.x, H3.y); PKFMA(7,  H3.z, H3.w);
        PKFMA(8,  H4.x, H4.y); PKFMA(9,  H4.z, H4.w);
        PKFMA(10, H5.x, H5.y); PKFMA(11, H5.z, H5.w);
        PKFMA(12, H6.x, H6.y); PKFMA(13, H6.z, H6.w);
        {
            accA = __builtin_elementwise_fma(wA[14], Ht, accA);
            accB = __builtin_elementwise_fma(wB[14], Ht, accB);
        }
        #undef PKFMA
        // input projection (x uniform, weights per-lane)
        accA = __builtin_elementwise_fma(xA[0], f32x2{x0, x1}, accA);
        accB = __builtin_elementwise_fma(xB[0], f32x2{x0, x1}, accB);
        accA = __builtin_elementwise_fma(xA[1], f32x2{x2v, x3}, accA);
        accB = __builtin_elementwise_fma(xB[1], f32x2{x2v, x3}, accB);
        accA = __builtin_elementwise_fma(xA[2], f32x2{x4, x5}, accA);
        accB = __builtin_elementwise_fma(xB[2], f32x2{x4, x5}, accB);

        const float aA = accA.x + accA.y;
        const float aB = accB.x + accB.y;

        // half0: nA=sigm_i, nB=sigm_f ; half1: nA=tanh_g, nB=sigm_o
        const float nA = fmaf(sA, rcp_(1.0f + exp2_(mA * aA)), cA);
        const float nB = rcp_(1.0f + exp2_(-1.4426950409f * aB));

        const float vA = __shfl_xor(nA, 32);
        const float vB = __shfl_xor(nB, 32);

        const float F = half ? vB : nB;   // sigm_f
        const float O = half ? nB : vB;   // sigm_o
        c = fmaf(F, c, nA * vA);          // nA*vA == sigm_i * tanh_g (both halves)
        const float tc = 1.0f - 2.0f * rcp_(exp2_(2.8853900818f * c) + 1.0f);
        h = O * tc;

        if (lane < HID) h_sh[e][lane] = h;   // low half writes
        asm volatile("s_waitcnt lgkmcnt(0)" ::: "memory");

        x0 = y0; x1 = y1; x2v = y2; x3 = y3; x4 = y4; x5 = y5;
    }

    // ---- FC1 (lanes 0..29): o1[u] = b1[u] + sum_k W1[u,k] * h[k] ----
    if (lane < HID) {
        float a1 = b1[lane];
        const float* w1r = W1 + lane * HID;
        #pragma unroll
        for (int k = 0; k < HID; ++k) a1 = fmaf(w1r[k], h_sh[e][k], a1);
        o1_sh[e][lane] = a1;
    }
    asm volatile("s_waitcnt lgkmcnt(0)" ::: "memory");

    // ---- FC2 (lanes 0..60): out[o] = b2[o] + sum_j W2[o,j] * o1[j] ----
    if (lane < NOUT) {
        float a2 = b2[lane];
        const float* w2r = W2 + lane * HID;
        #pragma unroll
        for (int k = 0; k < HID; ++k) a2 = fmaf(w2r[k], o1_sh[e][k], a2);
        out[(size_t)b * NOUT + lane] = a2;
    }
}

extern "C" void kernel_launch(void* const* d_in, const int* in_sizes, int n_in,
                              void* d_out, int out_size, void* d_ws, size_t ws_size,
                              hipStream_t stream) {
    const float* X   = (const float*)d_in[0];
    const float* Wih = (const float*)d_in[1];
    const float* Whh = (const float*)d_in[2];
    const float* bih = (const float*)d_in[3];
    const float* bhh = (const float*)d_in[4];
    const float* W1  = (const float*)d_in[5];
    const float* b1  = (const float*)d_in[6];
    const float* W2  = (const float*)d_in[7];
    const float* b2  = (const float*)d_in[8];
    float* out = (float*)d_out;

    dim3 grid(BATCH / WPB);   // 1024 blocks
    dim3 block(64 * WPB);     // 4 waves = 4 elements
    hipLaunchKernelGGL(lstm_fused3, grid, block, 0, stream,
                       X, Wih, Whh, bih, bhh, W1, b1, W2, b2, out);
}

// Round 4
// 350.160 us; speedup vs baseline: 1.3250x; 1.2856x over previous
//
#include <hip/hip_runtime.h>

// LSTMNet: SEQ=600, B=4096, IN=6, H=30, OUT=61, fp32.
// Layout A4: one wave = 2 batch elements; lane = 32*half + u; lane u<30 owns
// ALL FOUR gate rows (i,f,g,o) of hidden unit u for its element -> c,h update
// fully lane-local, no cross-lane exchange.
// Weights are loaded with OPAQUE inline-asm global_load_dwordx2 so the
// compiler cannot rematerialize them inside the 600-step loop (rounds 1-3
// failure mode). x prefetch is per-lane VMEM (vmcnt), so the per-step
// lgkmcnt fence only covers the single LDS h write.

#define SEQ   600
#define BATCH 4096
#define INP   6
#define HID   30
#define NOUT  61

typedef float f32x2 __attribute__((ext_vector_type(2)));

__device__ __forceinline__ float rcp_(float x)  { return __builtin_amdgcn_rcpf(x); }
__device__ __forceinline__ float exp2_(float x) { return __builtin_amdgcn_exp2f(x); }
#define LOG2E  1.4426950408889634f
#define LOG2E2 2.8853900817779268f

extern "C" __global__ void __launch_bounds__(64, 2)
lstm_fused4(const float* __restrict__ X,   const float* __restrict__ Wih,
            const float* __restrict__ Whh, const float* __restrict__ bih,
            const float* __restrict__ bhh, const float* __restrict__ W1,
            const float* __restrict__ b1,  const float* __restrict__ W2,
            const float* __restrict__ b2,  float* __restrict__ out)
{
    __shared__ float h_sh[2][32];    // one h row per element (pads unread)
    __shared__ float o1_sh[2][32];   // fc1 activations

    const int lane = threadIdx.x;        // 0..63
    const int half = lane >> 5;          // element slot in wave
    const int u    = lane & 31;          // hidden unit (active u < 30)
    const int uu   = (u < HID) ? u : (HID - 1);   // clamped row for safe loads
    const int b    = blockIdx.x * 2 + half;       // batch element
    const bool act = (u < HID);

    h_sh[half][u] = 0.0f;

    // ---- opaque weight loads: 4 gate rows x 15 k-pairs, + 4 x 3 input pairs ----
    const float* r0 = Whh + (0 * HID + uu) * HID;   // i
    const float* r1 = Whh + (1 * HID + uu) * HID;   // f
    const float* r2 = Whh + (2 * HID + uu) * HID;   // g
    const float* r3 = Whh + (3 * HID + uu) * HID;   // o

    f32x2 w0[15], w1[15], w2[15], w3[15];
    #pragma unroll
    for (int j = 0; j < 15; ++j) {
        asm volatile("global_load_dwordx2 %0, %1, off" : "=v"(w0[j]) : "v"(r0 + 2 * j));
        asm volatile("global_load_dwordx2 %0, %1, off" : "=v"(w1[j]) : "v"(r1 + 2 * j));
        asm volatile("global_load_dwordx2 %0, %1, off" : "=v"(w2[j]) : "v"(r2 + 2 * j));
        asm volatile("global_load_dwordx2 %0, %1, off" : "=v"(w3[j]) : "v"(r3 + 2 * j));
    }
    const float* s0 = Wih + (0 * HID + uu) * INP;
    const float* s1 = Wih + (1 * HID + uu) * INP;
    const float* s2 = Wih + (2 * HID + uu) * INP;
    const float* s3 = Wih + (3 * HID + uu) * INP;

    f32x2 xw0[3], xw1[3], xw2[3], xw3[3];
    #pragma unroll
    for (int j = 0; j < 3; ++j) {
        asm volatile("global_load_dwordx2 %0, %1, off" : "=v"(xw0[j]) : "v"(s0 + 2 * j));
        asm volatile("global_load_dwordx2 %0, %1, off" : "=v"(xw1[j]) : "v"(s1 + 2 * j));
        asm volatile("global_load_dwordx2 %0, %1, off" : "=v"(xw2[j]) : "v"(s2 + 2 * j));
        asm volatile("global_load_dwordx2 %0, %1, off" : "=v"(xw3[j]) : "v"(s3 + 2 * j));
    }
    asm volatile("s_waitcnt vmcnt(0)" ::: "memory");

    // biases (tiny; pinned scalars)
    float bb0 = 0.f, bb1 = 0.f, bb2 = 0.f, bb3 = 0.f;
    if (act) {
        bb0 = bih[0 * HID + u] + bhh[0 * HID + u];
        bb1 = bih[1 * HID + u] + bhh[1 * HID + u];
        bb2 = bih[2 * HID + u] + bhh[2 * HID + u];
        bb3 = bih[3 * HID + u] + bhh[3 * HID + u];
    }
    asm volatile("" : "+v"(bb0), "+v"(bb1), "+v"(bb2), "+v"(bb3));

    float c = 0.f, h = 0.f;

    // per-lane x (all lanes of a half load the same 24B line -> coalesced)
    f32x2 xc0, xc1, xc2, xn0, xn1, xn2;
    {
        const f32x2* p = (const f32x2*)(X + (size_t)b * INP);   // t = 0
        xc0 = p[0]; xc1 = p[1]; xc2 = p[2];
    }
    asm volatile("s_waitcnt lgkmcnt(0)" ::: "memory");   // h_sh init visible

    const float4* h4p = (const float4*)(&h_sh[half][0]);
    const f32x2*  h2p = (const f32x2*)(&h_sh[half][0]);

    for (int t = 0; t < SEQ; ++t) {
        // prefetch x for t+1 (VMEM; hidden under this step's compute)
        const int tn = (t + 1 < SEQ) ? (t + 1) : (SEQ - 1);
        const f32x2* p = (const f32x2*)(X + ((size_t)tn * BATCH + b) * INP);
        xn0 = p[0]; xn1 = p[1]; xn2 = p[2];

        // h: 7x float4 (k0..27) + 1x float2 (k28,29); broadcast within half
        float4 H0 = h4p[0], H1 = h4p[1], H2 = h4p[2], H3 = h4p[3];
        float4 H4 = h4p[4], H5 = h4p[5], H6 = h4p[6];
        f32x2  Ht = h2p[14];

        // two accumulation chains per gate (depth ~9 instead of 18)
        f32x2 a0e = f32x2{bb0, 0.f}, a0o = (f32x2)0.f;
        f32x2 a1e = f32x2{bb1, 0.f}, a1o = (f32x2)0.f;
        f32x2 a2e = f32x2{bb2, 0.f}, a2o = (f32x2)0.f;
        f32x2 a3e = f32x2{bb3, 0.f}, a3o = (f32x2)0.f;

        #define PK4(J, HX, HY, E)  do {                                   \
            f32x2 hv = f32x2{HX, HY};                                     \
            a0##E = __builtin_elementwise_fma(w0[J], hv, a0##E);          \
            a1##E = __builtin_elementwise_fma(w1[J], hv, a1##E);          \
            a2##E = __builtin_elementwise_fma(w2[J], hv, a2##E);          \
            a3##E = __builtin_elementwise_fma(w3[J], hv, a3##E);          \
        } while (0)
        PK4(0,  H0.x, H0.y, e); PK4(1,  H0.z, H0.w, o);
        PK4(2,  H1.x, H1.y, e); PK4(3,  H1.z, H1.w, o);
        PK4(4,  H2.x, H2.y, e); PK4(5,  H2.z, H2.w, o);
        PK4(6,  H3.x, H3.y, e); PK4(7,  H3.z, H3.w, o);
        PK4(8,  H4.x, H4.y, e); PK4(9,  H4.z, H4.w, o);
        PK4(10, H5.x, H5.y, e); PK4(11, H5.z, H5.w, o);
        PK4(12, H6.x, H6.y, e); PK4(13, H6.z, H6.w, o);
        {
            a0e = __builtin_elementwise_fma(w0[14], Ht, a0e);
            a1e = __builtin_elementwise_fma(w1[14], Ht, a1e);
            a2e = __builtin_elementwise_fma(w2[14], Ht, a2e);
            a3e = __builtin_elementwise_fma(w3[14], Ht, a3e);
        }
        #undef PK4
        // input projection
        a0o = __builtin_elementwise_fma(xw0[0], xc0, a0o);
        a1o = __builtin_elementwise_fma(xw1[0], xc0, a1o);
        a2o = __builtin_elementwise_fma(xw2[0], xc0, a2o);
        a3o = __builtin_elementwise_fma(xw3[0], xc0, a3o);
        a0e = __builtin_elementwise_fma(xw0[1], xc1, a0e);
        a1e = __builtin_elementwise_fma(xw1[1], xc1, a1e);
        a2e = __builtin_elementwise_fma(xw2[1], xc1, a2e);
        a3e = __builtin_elementwise_fma(xw3[1], xc1, a3e);
        a0o = __builtin_elementwise_fma(xw0[2], xc2, a0o);
        a1o = __builtin_elementwise_fma(xw1[2], xc2, a1o);
        a2o = __builtin_elementwise_fma(xw2[2], xc2, a2o);
        a3o = __builtin_elementwise_fma(xw3[2], xc2, a3o);

        const f32x2 g0v = a0e + a0o, g1v = a1e + a1o;
        const f32x2 g2v = a2e + a2o, g3v = a3e + a3o;
        const float g0 = g0v.x + g0v.y;   // i
        const float g1 = g1v.x + g1v.y;   // f
        const float g2 = g2v.x + g2v.y;   // g
        const float g3 = g3v.x + g3v.y;   // o

        const float si = rcp_(1.0f + exp2_(-LOG2E * g0));
        const float sf = rcp_(1.0f + exp2_(-LOG2E * g1));
        const float tg = 1.0f - 2.0f * rcp_(exp2_(LOG2E2 * g2) + 1.0f);
        const float so = rcp_(1.0f + exp2_(-LOG2E * g3));

        c = fmaf(sf, c, si * tg);
        const float tc = 1.0f - 2.0f * rcp_(exp2_(LOG2E2 * c) + 1.0f);
        h = so * tc;

        if (act) h_sh[half][u] = h;
        // drain only the DS write (x prefetch lives on vmcnt, untouched here)
        asm volatile("s_waitcnt lgkmcnt(0)" ::: "memory");

        xc0 = xn0; xc1 = xn1; xc2 = xn2;
    }

    // ---- FC1: o1[u] = b1[u] + sum_k W1[u,k] * h[k] ----
    if (act) {
        float a1 = b1[u];
        const float* w1r = W1 + u * HID;
        #pragma unroll
        for (int k = 0; k < HID; ++k) a1 = fmaf(w1r[k], h_sh[half][k], a1);
        o1_sh[half][u] = a1;
    }
    asm volatile("s_waitcnt lgkmcnt(0)" ::: "memory");

    // ---- FC2: out[o] = b2[o] + sum_j W2[o,j] * o1[j] ----
    if (act) {
        for (int o = u; o < NOUT; o += HID) {   // u=0 -> {0,30,60}, else {u,u+30}
            float a2 = b2[o];
            const float* w2r = W2 + o * HID;
            #pragma unroll
            for (int k = 0; k < HID; ++k) a2 = fmaf(w2r[k], o1_sh[half][k], a2);
            out[(size_t)b * NOUT + o] = a2;
        }
    }
}

extern "C" void kernel_launch(void* const* d_in, const int* in_sizes, int n_in,
                              void* d_out, int out_size, void* d_ws, size_t ws_size,
                              hipStream_t stream) {
    const float* X   = (const float*)d_in[0];
    const float* Wih = (const float*)d_in[1];
    const float* Whh = (const float*)d_in[2];
    const float* bih = (const float*)d_in[3];
    const float* bhh = (const float*)d_in[4];
    const float* W1  = (const float*)d_in[5];
    const float* b1  = (const float*)d_in[6];
    const float* W2  = (const float*)d_in[7];
    const float* b2  = (const float*)d_in[8];
    float* out = (float*)d_out;

    dim3 grid(BATCH / 2);   // 2048 blocks, 1 wave each (2 elements/wave)
    dim3 block(64);
    hipLaunchKernelGGL(lstm_fused4, grid, block, 0, stream,
                       X, Wih, Whh, bih, bhh, W1, b1, W2, b2, out);
}